// Round 7
// baseline (179.035 us; speedup 1.0000x reference)
//
#include <hip/hip_runtime.h>

// FactorizedSpectralConv2d: B=16, CIN=COUT=64, H=W=128, MH=MW=32, super_res=1
// kA (W-rDFT, GEMM) -> kB (H-DFT) -> kC (channel mix, ci-split + prefetch)
// -> kD (inv H-DFT, sums YF0+YF1) -> kE (inv W-rDFT + bias, GEMM).
// ws layout (64 MiB): A[0,32) -> XF[32,48) -> YF0[0,16) YF1[16,32) -> Z[32,64)

__device__ __forceinline__ void build_tab(float* tabs) {
    int t = threadIdx.x;
    if (t < 128) {
        float ang = (float)t * 0.049087385212340517f;  // 2*pi/128
        float s, c;
        sincosf(ang, &s, &c);
        tabs[t] = c;        // cos at [0..127]
        tabs[129 + t] = s;  // sin at [129..256]
    }
}

// ---- kA: A[row=(b,ci,h)][q=2kx+p] = rDFT_W(x)[kx], kx=0..31 ---------------
__global__ __launch_bounds__(256) void kA(const float* __restrict__ x,
                                          float* __restrict__ A) {
    __shared__ float tabs[258];
    __shared__ __align__(16) float Twid[64 * 64];   // [w][q], 16 KB
    __shared__ __align__(16) float xeo[16 * 260];   // 16.6 KB
    build_tab(tabs);
    __syncthreads();
    int t = threadIdx.x;
    size_t bc = blockIdx.x;  // b*64+ci, 1024 blocks
    #pragma unroll
    for (int i = 0; i < 16; ++i) {
        int e = t + i * 256;
        int w = e >> 6, q = e & 63, kx = q >> 1;
        int idx = (w * kx) & 127;
        float cv = tabs[idx], sv = tabs[129 + idx];
        Twid[e] = (q & 1) ? -sv : cv;
    }
    const float* xb = x + bc * 16384;
    int th = t & 15;        // h-group
    int tq = t >> 4;        // q-group
    int q0 = tq * 4;
    int wl4 = (t & 3) * 4;  // staging: w_l 0,4,8,12
    int hb  = t >> 2;       // staging: h 0..63 (+64)
    auto stage = [&](int ph) {
        #pragma unroll
        for (int it = 0; it < 2; ++it) {
            int h = it * 64 + hb;
            float4 lo = *(const float4*)(xb + h * 128 + ph * 16 + wl4);
            float4 hi = *(const float4*)(xb + h * 128 + ph * 16 + wl4 + 64);
            *(float2*)(&xeo[(wl4 + 0) * 260 + 2 * h]) = make_float2(lo.x + hi.x, lo.x - hi.x);
            *(float2*)(&xeo[(wl4 + 1) * 260 + 2 * h]) = make_float2(lo.y + hi.y, lo.y - hi.y);
            *(float2*)(&xeo[(wl4 + 2) * 260 + 2 * h]) = make_float2(lo.z + hi.z, lo.z - hi.z);
            *(float2*)(&xeo[(wl4 + 3) * 260 + 2 * h]) = make_float2(lo.w + hi.w, lo.w - hi.w);
        }
    };
    stage(0);
    float4 acc8[8];
    #pragma unroll
    for (int j = 0; j < 8; ++j) acc8[j] = make_float4(0.f, 0.f, 0.f, 0.f);
    for (int ph = 0; ph < 4; ++ph) {
        __syncthreads();
        #pragma unroll 4
        for (int wl = 0; wl < 16; ++wl) {
            int w = ph * 16 + wl;
            float4 tw = *(const float4*)(&Twid[w * 64 + q0]);
            const float* xr = &xeo[wl * 260 + 4 * th];
            #pragma unroll
            for (int i = 0; i < 4; ++i) {
                float4 d = *(const float4*)(xr + 64 * i);
                acc8[2*i].x   = fmaf(d.x, tw.x, acc8[2*i].x);
                acc8[2*i].y   = fmaf(d.x, tw.y, acc8[2*i].y);
                acc8[2*i].z   = fmaf(d.y, tw.z, acc8[2*i].z);
                acc8[2*i].w   = fmaf(d.y, tw.w, acc8[2*i].w);
                acc8[2*i+1].x = fmaf(d.z, tw.x, acc8[2*i+1].x);
                acc8[2*i+1].y = fmaf(d.z, tw.y, acc8[2*i+1].y);
                acc8[2*i+1].z = fmaf(d.w, tw.z, acc8[2*i+1].z);
                acc8[2*i+1].w = fmaf(d.w, tw.w, acc8[2*i+1].w);
            }
        }
        __syncthreads();
        if (ph < 3) stage(ph + 1);
    }
    #pragma unroll
    for (int i = 0; i < 4; ++i) {
        #pragma unroll
        for (int r = 0; r < 2; ++r) {
            int h = 32 * i + 2 * th + r;
            *(float4*)(A + (bc * 128 + h) * 64 + q0) = acc8[2*i + r];
        }
    }
}

// ---- kB: XF[(b,ci)][j*32+kx] = sum_h A[h][kx]*e^{-2pi i ky(j) h/128} ------
__global__ __launch_bounds__(256) void kB(const float* __restrict__ A,
                                          float* __restrict__ XF) {
    __shared__ float tabs[258];
    __shared__ float At[128 * 64];  // [h][2*kx+p], 32 KB
    build_tab(tabs);
    int t = threadIdx.x;
    size_t bc = blockIdx.x;  // b*64+ci, 1024 blocks
    const float4* src = (const float4*)(A + bc * 8192);
    float4* d4 = (float4*)At;
    #pragma unroll
    for (int i = 0; i < 8; ++i) d4[t + i * 256] = src[t + i * 256];
    __syncthreads();
    int j = t & 63;
    int kx0 = (t >> 6) * 8;
    int ky = (j < 32) ? j : j + 64;
    const float* cosT = tabs;
    const float* sinT = tabs + 129;
    float re[8] = {0, 0, 0, 0, 0, 0, 0, 0};
    float im[8] = {0, 0, 0, 0, 0, 0, 0, 0};
    int idx = 0;  // (ky*h) & 127
    for (int h = 0; h < 128; ++h) {
        float c = cosT[idx], s = sinT[idx];
        const float4* ap = (const float4*)(&At[h * 64 + 2 * kx0]);
        #pragma unroll
        for (int q4 = 0; q4 < 4; ++q4) {
            float4 av = ap[q4];
            int q0 = 2 * q4, q1 = 2 * q4 + 1;
            re[q0] = fmaf(av.x, c, re[q0]); re[q0] = fmaf(av.y, s, re[q0]);
            im[q0] = fmaf(av.y, c, im[q0]); im[q0] = fmaf(-av.x, s, im[q0]);
            re[q1] = fmaf(av.z, c, re[q1]); re[q1] = fmaf(av.w, s, re[q1]);
            im[q1] = fmaf(av.w, c, im[q1]); im[q1] = fmaf(-av.z, s, im[q1]);
        }
        idx = (idx + ky) & 127;
    }
    float* dst = XF + bc * 4096 + (size_t)(j * 32 + kx0) * 2;
    #pragma unroll
    for (int q4 = 0; q4 < 4; ++q4) {
        ((float4*)dst)[q4] =
            make_float4(re[2 * q4], im[2 * q4], re[2 * q4 + 1], im[2 * q4 + 1]);
    }
}

// ---- kC: channel mix, ci-split (2 partials) + register prefetch. ----------
// 1024 blocks = c(1b)<<9 | my(5b)<<4 | cot(2b)<<2 | mxh(1b)<<1 | cih(1b).
// Each block: 16b x 16co x 16mx outputs over 32 ci (4 chunks of 8), writes
// partial to YF0/YF1. Next chunk's global loads prefetched into registers.
__global__ __launch_bounds__(256) void kC(const float* __restrict__ XF,
                                          const float* __restrict__ Wgt,
                                          float* __restrict__ YF0,
                                          float* __restrict__ YF1) {
    __shared__ float2 Xs[2048];  // [ci_l][b][mx], 16 KB
    __shared__ float2 Ws[2048];  // [ci_l][co_l][mx], 16 KB
    int t = threadIdx.x;
    int bid = blockIdx.x;
    int cih = bid & 1;
    int mxh = (bid >> 1) & 1;
    int cot = (bid >> 2) & 3;
    int my  = (bid >> 4) & 31;
    int c   = bid >> 9;
    int co0 = cot * 16;
    int slotbase = (c * 32 + my) * 32 + mxh * 16;  // + mx, in [0,2048)
    int mx = t & 15;
    int b  = t >> 4;
    float2 acc[16];
    #pragma unroll
    for (int i = 0; i < 16; ++i) acc[i] = make_float2(0.f, 0.f);
    const size_t wre_base = (size_t)c * 4096 * 1024 + (size_t)my * 32 + mxh * 16;
    const size_t wim_base = wre_base + (size_t)2 * 4096 * 1024;
    float2 rx[8], rw[8];
    auto loadc = [&](int cc) {
        #pragma unroll
        for (int s = 0; s < 8; ++s) {
            int e = t + s * 256;
            int emx = e & 15, emid = (e >> 4) & 15, eci = e >> 8;
            int ci = cih * 32 + cc * 8 + eci;
            rx[s] = *(const float2*)(XF + ((size_t)(emid * 64 + ci) * 2048 + slotbase + emx) * 2);
            size_t g = (size_t)ci * 64 + co0 + emid;
            rw[s] = make_float2(Wgt[wre_base + g * 1024 + emx],
                                Wgt[wim_base + g * 1024 + emx]);
        }
    };
    loadc(0);
    for (int cc = 0; cc < 4; ++cc) {
        #pragma unroll
        for (int s = 0; s < 8; ++s) {
            int e = t + s * 256;
            Xs[e] = rx[s];
            Ws[e] = rw[s];
        }
        __syncthreads();
        if (cc < 3) loadc(cc + 1);  // prefetch hides under compute
        #pragma unroll
        for (int ci_l = 0; ci_l < 8; ++ci_l) {
            float2 xv = Xs[(ci_l * 16 + b) * 16 + mx];
            #pragma unroll
            for (int co_l = 0; co_l < 16; ++co_l) {
                float2 w = Ws[(ci_l * 16 + co_l) * 16 + mx];
                acc[co_l].x = fmaf(xv.x, w.x, acc[co_l].x);
                acc[co_l].x = fmaf(-xv.y, w.y, acc[co_l].x);
                acc[co_l].y = fmaf(xv.x, w.y, acc[co_l].y);
                acc[co_l].y = fmaf(xv.y, w.x, acc[co_l].y);
            }
        }
        __syncthreads();
    }
    float* YF = cih ? YF1 : YF0;
    #pragma unroll
    for (int co_l = 0; co_l < 16; ++co_l) {
        *(float2*)(YF + ((size_t)(b * 64 + co0 + co_l) * 2048 + slotbase + mx) * 2) = acc[co_l];
    }
}

// ---- kD: Z[(b,co)][h][kx] = sum_j (YF0+YF1)[j][kx]*e^{+2pi i h ky(j)/128} -
__global__ __launch_bounds__(256) void kD(const float* __restrict__ YF0,
                                          const float* __restrict__ YF1,
                                          float* __restrict__ Z) {
    __shared__ float tabs[258];
    __shared__ float Ys[4096];  // [j][kx][re,im], 16 KB
    build_tab(tabs);
    int t = threadIdx.x;
    size_t bo = blockIdx.x;  // b*64+co, 1024 blocks
    const float4* s0 = (const float4*)(YF0 + bo * 4096);
    const float4* s1 = (const float4*)(YF1 + bo * 4096);
    #pragma unroll
    for (int i = 0; i < 4; ++i) {
        float4 a = s0[t + i * 256], bb = s1[t + i * 256];
        ((float4*)Ys)[t + i * 256] =
            make_float4(a.x + bb.x, a.y + bb.y, a.z + bb.z, a.w + bb.w);
    }
    __syncthreads();
    int hl = t & 63;
    int kx0 = (t >> 6) * 8;
    const float* cosT = tabs;
    const float* sinT = tabs + 129;
    float ar[8] = {0,0,0,0,0,0,0,0}, ai[8] = {0,0,0,0,0,0,0,0};
    float br[8] = {0,0,0,0,0,0,0,0}, bi[8] = {0,0,0,0,0,0,0,0};
    int idx = 0;
    for (int j = 0; j < 64; ++j) {
        int ky = (j < 32) ? j : j + 64;
        float cc = cosT[idx], ss = sinT[idx];
        float sg = (ky & 1) ? -1.f : 1.f;
        float c2 = sg * cc, s2 = sg * ss;
        const float4* yp = (const float4*)(&Ys[(j * 32 + kx0) * 2]);
        #pragma unroll
        for (int q4 = 0; q4 < 4; ++q4) {
            float4 v = yp[q4];
            int q0 = 2 * q4, q1 = 2 * q4 + 1;
            ar[q0] = fmaf(v.x, cc, ar[q0]); ar[q0] = fmaf(-v.y, ss, ar[q0]);
            ai[q0] = fmaf(v.x, ss, ai[q0]); ai[q0] = fmaf(v.y, cc, ai[q0]);
            br[q0] = fmaf(v.x, c2, br[q0]); br[q0] = fmaf(-v.y, s2, br[q0]);
            bi[q0] = fmaf(v.x, s2, bi[q0]); bi[q0] = fmaf(v.y, c2, bi[q0]);
            ar[q1] = fmaf(v.z, cc, ar[q1]); ar[q1] = fmaf(-v.w, ss, ar[q1]);
            ai[q1] = fmaf(v.z, ss, ai[q1]); ai[q1] = fmaf(v.w, cc, ai[q1]);
            br[q1] = fmaf(v.z, c2, br[q1]); br[q1] = fmaf(-v.w, s2, br[q1]);
            bi[q1] = fmaf(v.z, s2, bi[q1]); bi[q1] = fmaf(v.w, c2, bi[q1]);
        }
        idx = (idx + hl) & 127;
        if (j == 31) idx = (idx + ((hl & 1) << 6)) & 127;  // ky jumps 31->96
    }
    float* d0 = Z + (bo * 128 + hl) * 64 + kx0 * 2;
    float* d1 = Z + (bo * 128 + hl + 64) * 64 + kx0 * 2;
    #pragma unroll
    for (int q4 = 0; q4 < 4; ++q4) {
        ((float4*)d0)[q4] = make_float4(ar[2*q4], ai[2*q4], ar[2*q4+1], ai[2*q4+1]);
        ((float4*)d1)[q4] = make_float4(br[2*q4], bi[2*q4], br[2*q4+1], bi[2*q4+1]);
    }
}

// ---- kE (GEMM-style): Y[h][w] = sum_q Z[h][q]*T[q][w] + bias --------------
__global__ __launch_bounds__(256) void kE(const float* __restrict__ Z,
                                          const float* __restrict__ bias,
                                          float* __restrict__ out) {
    __shared__ float tabs[258];
    __shared__ __align__(16) float Ts[64 * 128];  // 32 KB
    __shared__ __align__(16) float Zt[64 * 68];   // 17 KB, [q][h] stride 68
    build_tab(tabs);
    __syncthreads();
    int t = threadIdx.x;
    int bid = blockIdx.x;
    size_t bo = bid >> 1;          // b*64+co
    int hbase = (bid & 1) << 6;
    const float inv = 6.103515625e-05f;  // 1/16384
    #pragma unroll
    for (int i = 0; i < 32; ++i) {
        int e = t + i * 256;
        int q = e >> 7, w = e & 127;
        int k = q >> 1;
        int idx = (k * w) & 127;
        float val;
        if (q == 0)      val = inv;
        else if (q == 1) val = 0.f;
        else if (q & 1)  val = -2.f * inv * tabs[129 + idx];
        else             val =  2.f * inv * tabs[idx];
        Ts[e] = val;
    }
    const float* Zb = Z + (bo * 128 + hbase) * 64;
    #pragma unroll
    for (int s = 0; s < 4; ++s) {
        int u = t + s * 256;
        int h = u & 63, qg = u >> 6;
        float4 v = *(const float4*)(Zb + h * 64 + qg * 4);
        Zt[(qg * 4 + 0) * 68 + h] = v.x;
        Zt[(qg * 4 + 1) * 68 + h] = v.y;
        Zt[(qg * 4 + 2) * 68 + h] = v.z;
        Zt[(qg * 4 + 3) * 68 + h] = v.w;
    }
    __syncthreads();
    int w0 = (t & 31) * 4;
    int h0 = (t >> 5) * 8;
    float4 acc[8];
    #pragma unroll
    for (int j = 0; j < 8; ++j) acc[j] = make_float4(0.f, 0.f, 0.f, 0.f);
    #pragma unroll 2
    for (int q = 0; q < 64; ++q) {
        const float4* zp = (const float4*)(&Zt[q * 68 + h0]);
        float4 z0 = zp[0], z1 = zp[1];
        float4 tw = *(const float4*)(&Ts[q * 128 + w0]);
        acc[0].x = fmaf(z0.x, tw.x, acc[0].x); acc[0].y = fmaf(z0.x, tw.y, acc[0].y);
        acc[0].z = fmaf(z0.x, tw.z, acc[0].z); acc[0].w = fmaf(z0.x, tw.w, acc[0].w);
        acc[1].x = fmaf(z0.y, tw.x, acc[1].x); acc[1].y = fmaf(z0.y, tw.y, acc[1].y);
        acc[1].z = fmaf(z0.y, tw.z, acc[1].z); acc[1].w = fmaf(z0.y, tw.w, acc[1].w);
        acc[2].x = fmaf(z0.z, tw.x, acc[2].x); acc[2].y = fmaf(z0.z, tw.y, acc[2].y);
        acc[2].z = fmaf(z0.z, tw.z, acc[2].z); acc[2].w = fmaf(z0.z, tw.w, acc[2].w);
        acc[3].x = fmaf(z0.w, tw.x, acc[3].x); acc[3].y = fmaf(z0.w, tw.y, acc[3].y);
        acc[3].z = fmaf(z0.w, tw.z, acc[3].z); acc[3].w = fmaf(z0.w, tw.w, acc[3].w);
        acc[4].x = fmaf(z1.x, tw.x, acc[4].x); acc[4].y = fmaf(z1.x, tw.y, acc[4].y);
        acc[4].z = fmaf(z1.x, tw.z, acc[4].z); acc[4].w = fmaf(z1.x, tw.w, acc[4].w);
        acc[5].x = fmaf(z1.y, tw.x, acc[5].x); acc[5].y = fmaf(z1.y, tw.y, acc[5].y);
        acc[5].z = fmaf(z1.y, tw.z, acc[5].z); acc[5].w = fmaf(z1.y, tw.w, acc[5].w);
        acc[6].x = fmaf(z1.z, tw.x, acc[6].x); acc[6].y = fmaf(z1.z, tw.y, acc[6].y);
        acc[6].z = fmaf(z1.z, tw.z, acc[6].z); acc[6].w = fmaf(z1.z, tw.w, acc[6].w);
        acc[7].x = fmaf(z1.w, tw.x, acc[7].x); acc[7].y = fmaf(z1.w, tw.y, acc[7].y);
        acc[7].z = fmaf(z1.w, tw.z, acc[7].z); acc[7].w = fmaf(z1.w, tw.w, acc[7].w);
    }
    float bv = bias[(int)(bo & 63)];
    float* ob = out + ((size_t)(bo * 128 + hbase + h0)) * 128 + w0;
    #pragma unroll
    for (int j = 0; j < 8; ++j) {
        float4 r = acc[j];
        r.x += bv; r.y += bv; r.z += bv; r.w += bv;
        *(float4*)(ob + (size_t)j * 128) = r;
    }
}

extern "C" void kernel_launch(void* const* d_in, const int* in_sizes, int n_in,
                              void* d_out, int out_size, void* d_ws, size_t ws_size,
                              hipStream_t stream) {
    (void)in_sizes; (void)n_in; (void)out_size; (void)ws_size;
    const float* x    = (const float*)d_in[0];
    const float* wgt  = (const float*)d_in[1];
    const float* bias = (const float*)d_in[2];
    float* outp   = (float*)d_out;
    char* ws = (char*)d_ws;
    float* bufA   = (float*)(ws);                   // [0, 32 MiB)
    float* bufXF  = (float*)(ws + (32u << 20));     // [32, 48 MiB)
    float* bufYF0 = (float*)(ws);                   // [0, 16 MiB)  (A dead)
    float* bufYF1 = (float*)(ws + (16u << 20));     // [16, 32 MiB)
    float* bufZ   = (float*)(ws + (32u << 20));     // [32, 64 MiB) (XF dead)
    hipLaunchKernelGGL(kA, dim3(1024), dim3(256), 0, stream, x, bufA);
    hipLaunchKernelGGL(kB, dim3(1024), dim3(256), 0, stream, bufA, bufXF);
    hipLaunchKernelGGL(kC, dim3(1024), dim3(256), 0, stream, bufXF, wgt, bufYF0, bufYF1);
    hipLaunchKernelGGL(kD, dim3(1024), dim3(256), 0, stream, bufYF0, bufYF1, bufZ);
    hipLaunchKernelGGL(kE, dim3(2048), dim3(256), 0, stream, bufZ, bias, outp);
}

// Round 8
// 143.351 us; speedup vs baseline: 1.2489x; 1.2489x over previous
//
#include <hip/hip_runtime.h>

// FactorizedSpectralConv2d: B=16, CIN=COUT=64, H=W=128, MH=MW=32, super_res=1
// kA (W-rDFT, GEMM) -> kB (H-DFT, 4x symmetry-folded) -> kC (channel mix) ->
// kD (inv H-DFT, 4x folded, sums YF0+YF1) -> kE (inv W-rDFT + bias, GEMM).
// ws layout (64 MiB): A[0,32) -> XF[32,48) -> YF0[0,16) YF1[16,32) -> Z[32,64)

__device__ __forceinline__ void build_tab(float* tabs) {
    int t = threadIdx.x;
    if (t < 128) {
        float ang = (float)t * 0.049087385212340517f;  // 2*pi/128
        float s, c;
        sincosf(ang, &s, &c);
        tabs[t] = c;        // cos at [0..127]
        tabs[129 + t] = s;  // sin at [129..256]
    }
}

// ---- kA: A[row=(b,ci,h)][q=2kx+p] = rDFT_W(x)[kx], kx=0..31 ---------------
__global__ __launch_bounds__(256) void kA(const float* __restrict__ x,
                                          float* __restrict__ A) {
    __shared__ float tabs[258];
    __shared__ __align__(16) float Twid[64 * 64];   // [w][q], 16 KB
    __shared__ __align__(16) float xeo[16 * 260];   // 16.6 KB
    build_tab(tabs);
    __syncthreads();
    int t = threadIdx.x;
    size_t bc = blockIdx.x;  // b*64+ci, 1024 blocks
    #pragma unroll
    for (int i = 0; i < 16; ++i) {
        int e = t + i * 256;
        int w = e >> 6, q = e & 63, kx = q >> 1;
        int idx = (w * kx) & 127;
        float cv = tabs[idx], sv = tabs[129 + idx];
        Twid[e] = (q & 1) ? -sv : cv;
    }
    const float* xb = x + bc * 16384;
    int th = t & 15;
    int tq = t >> 4;
    int q0 = tq * 4;
    int wl4 = (t & 3) * 4;
    int hb  = t >> 2;
    auto stage = [&](int ph) {
        #pragma unroll
        for (int it = 0; it < 2; ++it) {
            int h = it * 64 + hb;
            float4 lo = *(const float4*)(xb + h * 128 + ph * 16 + wl4);
            float4 hi = *(const float4*)(xb + h * 128 + ph * 16 + wl4 + 64);
            *(float2*)(&xeo[(wl4 + 0) * 260 + 2 * h]) = make_float2(lo.x + hi.x, lo.x - hi.x);
            *(float2*)(&xeo[(wl4 + 1) * 260 + 2 * h]) = make_float2(lo.y + hi.y, lo.y - hi.y);
            *(float2*)(&xeo[(wl4 + 2) * 260 + 2 * h]) = make_float2(lo.z + hi.z, lo.z - hi.z);
            *(float2*)(&xeo[(wl4 + 3) * 260 + 2 * h]) = make_float2(lo.w + hi.w, lo.w - hi.w);
        }
    };
    stage(0);
    float4 acc8[8];
    #pragma unroll
    for (int j = 0; j < 8; ++j) acc8[j] = make_float4(0.f, 0.f, 0.f, 0.f);
    for (int ph = 0; ph < 4; ++ph) {
        __syncthreads();
        #pragma unroll 4
        for (int wl = 0; wl < 16; ++wl) {
            int w = ph * 16 + wl;
            float4 tw = *(const float4*)(&Twid[w * 64 + q0]);
            const float* xr = &xeo[wl * 260 + 4 * th];
            #pragma unroll
            for (int i = 0; i < 4; ++i) {
                float4 d = *(const float4*)(xr + 64 * i);
                acc8[2*i].x   = fmaf(d.x, tw.x, acc8[2*i].x);
                acc8[2*i].y   = fmaf(d.x, tw.y, acc8[2*i].y);
                acc8[2*i].z   = fmaf(d.y, tw.z, acc8[2*i].z);
                acc8[2*i].w   = fmaf(d.y, tw.w, acc8[2*i].w);
                acc8[2*i+1].x = fmaf(d.z, tw.x, acc8[2*i+1].x);
                acc8[2*i+1].y = fmaf(d.z, tw.y, acc8[2*i+1].y);
                acc8[2*i+1].z = fmaf(d.w, tw.z, acc8[2*i+1].z);
                acc8[2*i+1].w = fmaf(d.w, tw.w, acc8[2*i+1].w);
            }
        }
        __syncthreads();
        if (ph < 3) stage(ph + 1);
    }
    #pragma unroll
    for (int i = 0; i < 4; ++i) {
        #pragma unroll
        for (int r = 0; r < 2; ++r) {
            int h = 32 * i + 2 * th + r;
            *(float4*)(A + (bc * 128 + h) * 64 + q0) = acc8[2*i + r];
        }
    }
}

// ---- kB (folded): XF[j][kx] over retained ky {0..31, 96..127}. ------------
// Pairs (k, 64-k) share chains: P1=Σ ar·c, P2=Σ ai·s, P3=Σ ai·c, P4=Σ ar·s.
// XF[k] = (P1+P2, P3-P4); XF[64-k] = (P1-P2, P3+P4). h-fold: planes
// Af[p][m][q]: p0=A[2m]+A[2m+64], p1=A[2m]-A[2m+64], p2=A[2m+1]+A[2m+65],
// p3=A[2m+1]-A[2m+65]; lane k uses sigma=k&1 planes. Row 32 via mini-epilogue.
__global__ __launch_bounds__(256) void kB(const float* __restrict__ A,
                                          float* __restrict__ XF) {
    __shared__ float tabs[258];
    __shared__ __align__(16) float Af[4 * 2048];  // 32 KB
    build_tab(tabs);
    int t = threadIdx.x;
    size_t bc = blockIdx.x;  // b*64+ci, 1024 blocks
    const float* Ab = A + bc * 8192;
    #pragma unroll
    for (int uu = 0; uu < 2; ++uu) {
        int u = t + uu * 256;
        int m = u >> 4, qf = (u & 15) * 4;
        float4 e0 = *(const float4*)(Ab + (2*m)      * 64 + qf);
        float4 e1 = *(const float4*)(Ab + (2*m + 64) * 64 + qf);
        float4 o0 = *(const float4*)(Ab + (2*m + 1)  * 64 + qf);
        float4 o1 = *(const float4*)(Ab + (2*m + 65) * 64 + qf);
        *(float4*)(&Af[       m*64 + qf]) = make_float4(e0.x+e1.x, e0.y+e1.y, e0.z+e1.z, e0.w+e1.w);
        *(float4*)(&Af[2048 + m*64 + qf]) = make_float4(e0.x-e1.x, e0.y-e1.y, e0.z-e1.z, e0.w-e1.w);
        *(float4*)(&Af[4096 + m*64 + qf]) = make_float4(o0.x+o1.x, o0.y+o1.y, o0.z+o1.z, o0.w+o1.w);
        *(float4*)(&Af[6144 + m*64 + qf]) = make_float4(o0.x-o1.x, o0.y-o1.y, o0.z-o1.z, o0.w-o1.w);
    }
    __syncthreads();
    int k = t & 31, kxg = t >> 5;
    int kx0 = kxg * 4;
    int sig = k & 1;
    const float* pe = Af + sig * 2048;
    const float* po = Af + 4096 + sig * 2048;
    float4 P1 = {0,0,0,0}, P2 = {0,0,0,0}, P3 = {0,0,0,0}, P4 = {0,0,0,0};
    int idx_e = 0;
    for (int m = 0; m < 32; ++m) {
        float ce = tabs[idx_e], se = tabs[129 + idx_e];
        int idx_o = (idx_e + k) & 127;
        float co_ = tabs[idx_o], so_ = tabs[129 + idx_o];
        idx_e = (idx_e + 2 * k) & 127;
        float4 ae01 = *(const float4*)(pe + m * 64 + 2 * kx0);
        float4 ae23 = *(const float4*)(pe + m * 64 + 2 * kx0 + 4);
        float4 ao01 = *(const float4*)(po + m * 64 + 2 * kx0);
        float4 ao23 = *(const float4*)(po + m * 64 + 2 * kx0 + 4);
        P1.x = fmaf(ae01.x, ce, P1.x); P1.x = fmaf(ao01.x, co_, P1.x);
        P2.x = fmaf(ae01.y, se, P2.x); P2.x = fmaf(ao01.y, so_, P2.x);
        P3.x = fmaf(ae01.y, ce, P3.x); P3.x = fmaf(ao01.y, co_, P3.x);
        P4.x = fmaf(ae01.x, se, P4.x); P4.x = fmaf(ao01.x, so_, P4.x);
        P1.y = fmaf(ae01.z, ce, P1.y); P1.y = fmaf(ao01.z, co_, P1.y);
        P2.y = fmaf(ae01.w, se, P2.y); P2.y = fmaf(ao01.w, so_, P2.y);
        P3.y = fmaf(ae01.w, ce, P3.y); P3.y = fmaf(ao01.w, co_, P3.y);
        P4.y = fmaf(ae01.z, se, P4.y); P4.y = fmaf(ao01.z, so_, P4.y);
        P1.z = fmaf(ae23.x, ce, P1.z); P1.z = fmaf(ao23.x, co_, P1.z);
        P2.z = fmaf(ae23.y, se, P2.z); P2.z = fmaf(ao23.y, so_, P2.z);
        P3.z = fmaf(ae23.y, ce, P3.z); P3.z = fmaf(ao23.y, co_, P3.z);
        P4.z = fmaf(ae23.x, se, P4.z); P4.z = fmaf(ao23.x, so_, P4.z);
        P1.w = fmaf(ae23.z, ce, P1.w); P1.w = fmaf(ao23.z, co_, P1.w);
        P2.w = fmaf(ae23.w, se, P2.w); P2.w = fmaf(ao23.w, so_, P2.w);
        P3.w = fmaf(ae23.w, ce, P3.w); P3.w = fmaf(ao23.w, co_, P3.w);
        P4.w = fmaf(ae23.z, se, P4.w); P4.w = fmaf(ao23.z, so_, P4.w);
    }
    float* xfb = XF + bc * 4096;
    // row k: (P1+P2, P3-P4)
    *(float4*)(xfb + (k * 32 + kx0) * 2) =
        make_float4(P1.x + P2.x, P3.x - P4.x, P1.y + P2.y, P3.y - P4.y);
    *(float4*)(xfb + (k * 32 + kx0) * 2 + 4) =
        make_float4(P1.z + P2.z, P3.z - P4.z, P1.w + P2.w, P3.w - P4.w);
    // row 64-k: (P1-P2, P3+P4), skip k==0
    if (k) {
        *(float4*)(xfb + ((64 - k) * 32 + kx0) * 2) =
            make_float4(P1.x - P2.x, P3.x + P4.x, P1.y - P2.y, P3.y + P4.y);
        *(float4*)(xfb + ((64 - k) * 32 + kx0) * 2 + 4) =
            make_float4(P1.z - P2.z, P3.z + P4.z, P1.w - P2.w, P3.w + P4.w);
    }
    // row 32 (ky=96): re = Σ(-1)^m(aep.x - aop.y), im = Σ(-1)^m(aep.y + aop.x)
    if (t < 32) {
        int kx = t;
        float re = 0.f, im = 0.f;
        #pragma unroll 8
        for (int m = 0; m < 32; ++m) {
            float2 aep = *(const float2*)(&Af[       m * 64 + 2 * kx]);
            float2 aop = *(const float2*)(&Af[4096 + m * 64 + 2 * kx]);
            float sg = (m & 1) ? -1.f : 1.f;
            re = fmaf(sg, aep.x - aop.y, re);
            im = fmaf(sg, aep.y + aop.x, im);
        }
        xfb[(32 * 32 + kx) * 2]     = re;
        xfb[(32 * 32 + kx) * 2 + 1] = im;
    }
}

// ---- kC: channel mix, ci-split (2 partials) + register prefetch. ----------
__global__ __launch_bounds__(256) void kC(const float* __restrict__ XF,
                                          const float* __restrict__ Wgt,
                                          float* __restrict__ YF0,
                                          float* __restrict__ YF1) {
    __shared__ float2 Xs[2048];  // 16 KB
    __shared__ float2 Ws[2048];  // 16 KB
    int t = threadIdx.x;
    int bid = blockIdx.x;
    int cih = bid & 1;
    int mxh = (bid >> 1) & 1;
    int cot = (bid >> 2) & 3;
    int my  = (bid >> 4) & 31;
    int c   = bid >> 9;
    int co0 = cot * 16;
    int slotbase = (c * 32 + my) * 32 + mxh * 16;
    int mx = t & 15;
    int b  = t >> 4;
    float2 acc[16];
    #pragma unroll
    for (int i = 0; i < 16; ++i) acc[i] = make_float2(0.f, 0.f);
    const size_t wre_base = (size_t)c * 4096 * 1024 + (size_t)my * 32 + mxh * 16;
    const size_t wim_base = wre_base + (size_t)2 * 4096 * 1024;
    float2 rx[8], rw[8];
    auto loadc = [&](int cc) {
        #pragma unroll
        for (int s = 0; s < 8; ++s) {
            int e = t + s * 256;
            int emx = e & 15, emid = (e >> 4) & 15, eci = e >> 8;
            int ci = cih * 32 + cc * 8 + eci;
            rx[s] = *(const float2*)(XF + ((size_t)(emid * 64 + ci) * 2048 + slotbase + emx) * 2);
            size_t g = (size_t)ci * 64 + co0 + emid;
            rw[s] = make_float2(Wgt[wre_base + g * 1024 + emx],
                                Wgt[wim_base + g * 1024 + emx]);
        }
    };
    loadc(0);
    for (int cc = 0; cc < 4; ++cc) {
        #pragma unroll
        for (int s = 0; s < 8; ++s) {
            int e = t + s * 256;
            Xs[e] = rx[s];
            Ws[e] = rw[s];
        }
        __syncthreads();
        if (cc < 3) loadc(cc + 1);
        #pragma unroll
        for (int ci_l = 0; ci_l < 8; ++ci_l) {
            float2 xv = Xs[(ci_l * 16 + b) * 16 + mx];
            #pragma unroll
            for (int co_l = 0; co_l < 16; ++co_l) {
                float2 w = Ws[(ci_l * 16 + co_l) * 16 + mx];
                acc[co_l].x = fmaf(xv.x, w.x, acc[co_l].x);
                acc[co_l].x = fmaf(-xv.y, w.y, acc[co_l].x);
                acc[co_l].y = fmaf(xv.x, w.y, acc[co_l].y);
                acc[co_l].y = fmaf(xv.y, w.x, acc[co_l].y);
            }
        }
        __syncthreads();
    }
    float* YF = cih ? YF1 : YF0;
    #pragma unroll
    for (int co_l = 0; co_l < 16; ++co_l) {
        *(float2*)(YF + ((size_t)(b * 64 + co0 + co_l) * 2048 + slotbase + mx) * 2) = acc[co_l];
    }
}

// ---- kD (folded): Z[h][kx] = Σ_{k=0..32} C_k(h)·Q[k] + i·S_k(h)·R[k] ------
// Q[k]=Y[k]+Y[64-k], R[k]=Y[k]-Y[64-k] (k=1..31); Q[0]=Y[0],R[0]=0;
// Q[32]=Y[32],R[32]=-Y[32]. h-fold: Ee (even k) / Eo (odd k);
// Z[h]=Ee+Eo, Z[h+64]=Ee-Eo.
__global__ __launch_bounds__(256) void kD(const float* __restrict__ YF0,
                                          const float* __restrict__ YF1,
                                          float* __restrict__ Z) {
    __shared__ float tabs[258];
    __shared__ __align__(16) float Qs[33 * 64];  // 8.25 KB
    __shared__ __align__(16) float Rs[33 * 64];  // 8.25 KB
    build_tab(tabs);
    int t = threadIdx.x;
    size_t bo = blockIdx.x;  // b*64+co, 1024 blocks
    const float* y0 = YF0 + bo * 4096;
    const float* y1 = YF1 + bo * 4096;
    for (int u = t; u < 528; u += 256) {
        int k = u >> 4, kxf = (u & 15) * 4;
        float4 a0 = *(const float4*)(y0 + k * 64 + kxf);
        float4 a1 = *(const float4*)(y1 + k * 64 + kxf);
        float4 a = make_float4(a0.x+a1.x, a0.y+a1.y, a0.z+a1.z, a0.w+a1.w);
        float4 Q, R;
        if (k == 0) { Q = a; R = make_float4(0.f, 0.f, 0.f, 0.f); }
        else if (k == 32) { Q = a; R = make_float4(-a.x, -a.y, -a.z, -a.w); }
        else {
            float4 b0 = *(const float4*)(y0 + (64 - k) * 64 + kxf);
            float4 b1 = *(const float4*)(y1 + (64 - k) * 64 + kxf);
            float4 bb = make_float4(b0.x+b1.x, b0.y+b1.y, b0.z+b1.z, b0.w+b1.w);
            Q = make_float4(a.x+bb.x, a.y+bb.y, a.z+bb.z, a.w+bb.w);
            R = make_float4(a.x-bb.x, a.y-bb.y, a.z-bb.z, a.w-bb.w);
        }
        *(float4*)(&Qs[k * 64 + kxf]) = Q;
        *(float4*)(&Rs[k * 64 + kxf]) = R;
    }
    __syncthreads();
    int hh = t >> 2;            // 0..63; outputs rows hh and hh+64
    int kx0 = (t & 3) * 8;
    float4 Ee0 = {0,0,0,0}, Ee1 = {0,0,0,0}, Ee2 = {0,0,0,0}, Ee3 = {0,0,0,0};
    float4 Eo0 = {0,0,0,0}, Eo1 = {0,0,0,0}, Eo2 = {0,0,0,0}, Eo3 = {0,0,0,0};
    int idx = 0;
#define KD_BODY(E0, E1, E2, E3, kk)                                          \
    {                                                                        \
        float c = tabs[idx], s = tabs[129 + idx];                            \
        const float4* Qp = (const float4*)(&Qs[(kk) * 64 + kx0 * 2]);        \
        const float4* Rp = (const float4*)(&Rs[(kk) * 64 + kx0 * 2]);        \
        float4 Qv, Rv;                                                       \
        Qv = Qp[0]; Rv = Rp[0];                                              \
        E0.x = fmaf(c, Qv.x, E0.x); E0.x = fmaf(-s, Rv.y, E0.x);             \
        E0.y = fmaf(c, Qv.y, E0.y); E0.y = fmaf(s, Rv.x, E0.y);              \
        E0.z = fmaf(c, Qv.z, E0.z); E0.z = fmaf(-s, Rv.w, E0.z);             \
        E0.w = fmaf(c, Qv.w, E0.w); E0.w = fmaf(s, Rv.z, E0.w);              \
        Qv = Qp[1]; Rv = Rp[1];                                              \
        E1.x = fmaf(c, Qv.x, E1.x); E1.x = fmaf(-s, Rv.y, E1.x);             \
        E1.y = fmaf(c, Qv.y, E1.y); E1.y = fmaf(s, Rv.x, E1.y);              \
        E1.z = fmaf(c, Qv.z, E1.z); E1.z = fmaf(-s, Rv.w, E1.z);             \
        E1.w = fmaf(c, Qv.w, E1.w); E1.w = fmaf(s, Rv.z, E1.w);              \
        Qv = Qp[2]; Rv = Rp[2];                                              \
        E2.x = fmaf(c, Qv.x, E2.x); E2.x = fmaf(-s, Rv.y, E2.x);             \
        E2.y = fmaf(c, Qv.y, E2.y); E2.y = fmaf(s, Rv.x, E2.y);              \
        E2.z = fmaf(c, Qv.z, E2.z); E2.z = fmaf(-s, Rv.w, E2.z);             \
        E2.w = fmaf(c, Qv.w, E2.w); E2.w = fmaf(s, Rv.z, E2.w);              \
        Qv = Qp[3]; Rv = Rp[3];                                              \
        E3.x = fmaf(c, Qv.x, E3.x); E3.x = fmaf(-s, Rv.y, E3.x);             \
        E3.y = fmaf(c, Qv.y, E3.y); E3.y = fmaf(s, Rv.x, E3.y);              \
        E3.z = fmaf(c, Qv.z, E3.z); E3.z = fmaf(-s, Rv.w, E3.z);             \
        E3.w = fmaf(c, Qv.w, E3.w); E3.w = fmaf(s, Rv.z, E3.w);              \
        idx = (idx + hh) & 127;                                              \
    }
    for (int u = 0; u < 16; ++u) {
        KD_BODY(Ee0, Ee1, Ee2, Ee3, 2 * u);
        KD_BODY(Eo0, Eo1, Eo2, Eo3, 2 * u + 1);
    }
    KD_BODY(Ee0, Ee1, Ee2, Ee3, 32);
#undef KD_BODY
    float* d0 = Z + (bo * 128 + hh) * 64 + kx0 * 2;
    float* d1 = Z + (bo * 128 + hh + 64) * 64 + kx0 * 2;
    ((float4*)d0)[0] = make_float4(Ee0.x+Eo0.x, Ee0.y+Eo0.y, Ee0.z+Eo0.z, Ee0.w+Eo0.w);
    ((float4*)d0)[1] = make_float4(Ee1.x+Eo1.x, Ee1.y+Eo1.y, Ee1.z+Eo1.z, Ee1.w+Eo1.w);
    ((float4*)d0)[2] = make_float4(Ee2.x+Eo2.x, Ee2.y+Eo2.y, Ee2.z+Eo2.z, Ee2.w+Eo2.w);
    ((float4*)d0)[3] = make_float4(Ee3.x+Eo3.x, Ee3.y+Eo3.y, Ee3.z+Eo3.z, Ee3.w+Eo3.w);
    ((float4*)d1)[0] = make_float4(Ee0.x-Eo0.x, Ee0.y-Eo0.y, Ee0.z-Eo0.z, Ee0.w-Eo0.w);
    ((float4*)d1)[1] = make_float4(Ee1.x-Eo1.x, Ee1.y-Eo1.y, Ee1.z-Eo1.z, Ee1.w-Eo1.w);
    ((float4*)d1)[2] = make_float4(Ee2.x-Eo2.x, Ee2.y-Eo2.y, Ee2.z-Eo2.z, Ee2.w-Eo2.w);
    ((float4*)d1)[3] = make_float4(Ee3.x-Eo3.x, Ee3.y-Eo3.y, Ee3.z-Eo3.z, Ee3.w-Eo3.w);
}

// ---- kE (GEMM-style): Y[h][w] = sum_q Z[h][q]*T[q][w] + bias --------------
__global__ __launch_bounds__(256) void kE(const float* __restrict__ Z,
                                          const float* __restrict__ bias,
                                          float* __restrict__ out) {
    __shared__ float tabs[258];
    __shared__ __align__(16) float Ts[64 * 128];  // 32 KB
    __shared__ __align__(16) float Zt[64 * 68];   // 17 KB
    build_tab(tabs);
    __syncthreads();
    int t = threadIdx.x;
    int bid = blockIdx.x;
    size_t bo = bid >> 1;
    int hbase = (bid & 1) << 6;
    const float inv = 6.103515625e-05f;  // 1/16384
    #pragma unroll
    for (int i = 0; i < 32; ++i) {
        int e = t + i * 256;
        int q = e >> 7, w = e & 127;
        int k = q >> 1;
        int idx = (k * w) & 127;
        float val;
        if (q == 0)      val = inv;
        else if (q == 1) val = 0.f;
        else if (q & 1)  val = -2.f * inv * tabs[129 + idx];
        else             val =  2.f * inv * tabs[idx];
        Ts[e] = val;
    }
    const float* Zb = Z + (bo * 128 + hbase) * 64;
    #pragma unroll
    for (int s = 0; s < 4; ++s) {
        int u = t + s * 256;
        int h = u & 63, qg = u >> 6;
        float4 v = *(const float4*)(Zb + h * 64 + qg * 4);
        Zt[(qg * 4 + 0) * 68 + h] = v.x;
        Zt[(qg * 4 + 1) * 68 + h] = v.y;
        Zt[(qg * 4 + 2) * 68 + h] = v.z;
        Zt[(qg * 4 + 3) * 68 + h] = v.w;
    }
    __syncthreads();
    int w0 = (t & 31) * 4;
    int h0 = (t >> 5) * 8;
    float4 acc[8];
    #pragma unroll
    for (int j = 0; j < 8; ++j) acc[j] = make_float4(0.f, 0.f, 0.f, 0.f);
    #pragma unroll 2
    for (int q = 0; q < 64; ++q) {
        const float4* zp = (const float4*)(&Zt[q * 68 + h0]);
        float4 z0 = zp[0], z1 = zp[1];
        float4 tw = *(const float4*)(&Ts[q * 128 + w0]);
        acc[0].x = fmaf(z0.x, tw.x, acc[0].x); acc[0].y = fmaf(z0.x, tw.y, acc[0].y);
        acc[0].z = fmaf(z0.x, tw.z, acc[0].z); acc[0].w = fmaf(z0.x, tw.w, acc[0].w);
        acc[1].x = fmaf(z0.y, tw.x, acc[1].x); acc[1].y = fmaf(z0.y, tw.y, acc[1].y);
        acc[1].z = fmaf(z0.y, tw.z, acc[1].z); acc[1].w = fmaf(z0.y, tw.w, acc[1].w);
        acc[2].x = fmaf(z0.z, tw.x, acc[2].x); acc[2].y = fmaf(z0.z, tw.y, acc[2].y);
        acc[2].z = fmaf(z0.z, tw.z, acc[2].z); acc[2].w = fmaf(z0.z, tw.w, acc[2].w);
        acc[3].x = fmaf(z0.w, tw.x, acc[3].x); acc[3].y = fmaf(z0.w, tw.y, acc[3].y);
        acc[3].z = fmaf(z0.w, tw.z, acc[3].z); acc[3].w = fmaf(z0.w, tw.w, acc[3].w);
        acc[4].x = fmaf(z1.x, tw.x, acc[4].x); acc[4].y = fmaf(z1.x, tw.y, acc[4].y);
        acc[4].z = fmaf(z1.x, tw.z, acc[4].z); acc[4].w = fmaf(z1.x, tw.w, acc[4].w);
        acc[5].x = fmaf(z1.y, tw.x, acc[5].x); acc[5].y = fmaf(z1.y, tw.y, acc[5].y);
        acc[5].z = fmaf(z1.y, tw.z, acc[5].z); acc[5].w = fmaf(z1.y, tw.w, acc[5].w);
        acc[6].x = fmaf(z1.z, tw.x, acc[6].x); acc[6].y = fmaf(z1.z, tw.y, acc[6].y);
        acc[6].z = fmaf(z1.z, tw.z, acc[6].z); acc[6].w = fmaf(z1.z, tw.w, acc[6].w);
        acc[7].x = fmaf(z1.w, tw.x, acc[7].x); acc[7].y = fmaf(z1.w, tw.y, acc[7].y);
        acc[7].z = fmaf(z1.w, tw.z, acc[7].z); acc[7].w = fmaf(z1.w, tw.w, acc[7].w);
    }
    float bv = bias[(int)(bo & 63)];
    float* ob = out + ((size_t)(bo * 128 + hbase + h0)) * 128 + w0;
    #pragma unroll
    for (int j = 0; j < 8; ++j) {
        float4 r = acc[j];
        r.x += bv; r.y += bv; r.z += bv; r.w += bv;
        *(float4*)(ob + (size_t)j * 128) = r;
    }
}

extern "C" void kernel_launch(void* const* d_in, const int* in_sizes, int n_in,
                              void* d_out, int out_size, void* d_ws, size_t ws_size,
                              hipStream_t stream) {
    (void)in_sizes; (void)n_in; (void)out_size; (void)ws_size;
    const float* x    = (const float*)d_in[0];
    const float* wgt  = (const float*)d_in[1];
    const float* bias = (const float*)d_in[2];
    float* outp   = (float*)d_out;
    char* ws = (char*)d_ws;
    float* bufA   = (float*)(ws);                   // [0, 32 MiB)
    float* bufXF  = (float*)(ws + (32u << 20));     // [32, 48 MiB)
    float* bufYF0 = (float*)(ws);                   // [0, 16 MiB)  (A dead)
    float* bufYF1 = (float*)(ws + (16u << 20));     // [16, 32 MiB)
    float* bufZ   = (float*)(ws + (32u << 20));     // [32, 64 MiB) (XF dead)
    hipLaunchKernelGGL(kA, dim3(1024), dim3(256), 0, stream, x, bufA);
    hipLaunchKernelGGL(kB, dim3(1024), dim3(256), 0, stream, bufA, bufXF);
    hipLaunchKernelGGL(kC, dim3(1024), dim3(256), 0, stream, bufXF, wgt, bufYF0, bufYF1);
    hipLaunchKernelGGL(kD, dim3(1024), dim3(256), 0, stream, bufYF0, bufYF1, bufZ);
    hipLaunchKernelGGL(kE, dim3(2048), dim3(256), 0, stream, bufZ, bias, outp);
}